// Round 7
// baseline (4848.264 us; speedup 1.0000x reference)
//
#include <hip/hip_runtime.h>

typedef __attribute__((ext_vector_type(8))) short s16x8;
typedef __attribute__((ext_vector_type(4))) float fx4;

static __device__ __forceinline__ unsigned short f2bf(float f){
  unsigned u = __float_as_uint(f);
  return (unsigned short)((u + 0x7fffu + ((u>>16)&1u)) >> 16);   // RNE
}
static __device__ __forceinline__ float bf2f(unsigned short s){
  return __uint_as_float(((unsigned)s)<<16);
}
// L1-bypassing L2-point load (sc0). asm volatile + memory clobber => cannot
// be hoisted, merged, or served from L1. (R5 lesson: fetch_add(0) gets
// canonicalized to an L1-cacheable atomic load -> stale-spin deadlock.)
static __device__ __forceinline__ unsigned ld_flag_sc0(const unsigned* p){
  unsigned v;
  asm volatile("global_load_dword %0, %1, off sc0\n\t"
               "s_waitcnt vmcnt(0)"
               : "=v"(v) : "v"(p) : "memory");
  return v;
}

// ---------------------------------------------------------------- W_out -> bf16
__global__ void k_cvt_wout(const float* __restrict__ w, unsigned short* __restrict__ o){
  int g = blockIdx.x*256 + threadIdx.x;
  int idx = g*4;
  float4 f = *(const float4*)(w + idx);
  unsigned u0 = (unsigned)f2bf(f.x) | ((unsigned)f2bf(f.y)<<16);
  unsigned u1 = (unsigned)f2bf(f.z) | ((unsigned)f2bf(f.w)<<16);
  *(uint2*)(o + idx) = make_uint2(u0, u1);
}

// ---------------------------------------------------------------- GEMM1: xp = x@W_ih^T + (b_ih+b_hh)
__global__ __launch_bounds__(256) void k_gemm_xp(
    const float* __restrict__ X, const float* __restrict__ Wih,
    const float* __restrict__ bih, const float* __restrict__ bhh,
    unsigned short* __restrict__ XP){
  __shared__ unsigned short As[128][40];
  __shared__ unsigned short Bs[128][40];
  const int bm = blockIdx.x, bn = blockIdx.y;
  const int tid = threadIdx.x, w = tid>>6, l = tid&63;
  const int wm = w>>1, wn = w&1;
  const int m0 = bm*128, n0 = bn*128;
  fx4 acc[4][4] = {};
  for (int kb = 0; kb < 512; kb += 32){
    #pragma unroll
    for (int q=0;q<4;q++){
      int f = tid + q*256;
      int row = f>>3, c4 = (f&7)*4;
      float4 v = *(const float4*)(X + (m0+row)*512 + kb + c4);
      unsigned u0 = (unsigned)f2bf(v.x) | ((unsigned)f2bf(v.y)<<16);
      unsigned u1 = (unsigned)f2bf(v.z) | ((unsigned)f2bf(v.w)<<16);
      *(uint2*)&As[row][c4] = make_uint2(u0,u1);
    }
    #pragma unroll
    for (int q=0;q<4;q++){
      int f = tid + q*256;
      int row = f>>3, c4 = (f&7)*4;
      float4 v = *(const float4*)(Wih + (n0+row)*512 + kb + c4);
      unsigned u0 = (unsigned)f2bf(v.x) | ((unsigned)f2bf(v.y)<<16);
      unsigned u1 = (unsigned)f2bf(v.z) | ((unsigned)f2bf(v.w)<<16);
      *(uint2*)&Bs[row][c4] = make_uint2(u0,u1);
    }
    __syncthreads();
    const int kbase = (l>>4)*8;
    s16x8 a[4], b[4];
    #pragma unroll
    for (int mt=0;mt<4;mt++) a[mt] = *(const s16x8*)&As[wm*64 + mt*16 + (l&15)][kbase];
    #pragma unroll
    for (int nt=0;nt<4;nt++) b[nt] = *(const s16x8*)&Bs[wn*64 + nt*16 + (l&15)][kbase];
    #pragma unroll
    for (int mt=0;mt<4;mt++)
      #pragma unroll
      for (int nt=0;nt<4;nt++)
        acc[mt][nt] = __builtin_amdgcn_mfma_f32_16x16x32_bf16(a[mt], b[nt], acc[mt][nt], 0,0,0);
    __syncthreads();
  }
  #pragma unroll
  for (int nt=0;nt<4;nt++){
    int n = n0 + wn*64 + nt*16 + (l&15);
    float bias = bih[n] + bhh[n];
    #pragma unroll
    for (int mt=0;mt<4;mt++){
      #pragma unroll
      for (int r=0;r<4;r++){
        int grow = m0 + wm*64 + mt*16 + (l>>4)*4 + r;   // = b*1024 + t
        int bb = grow >> 10, t = grow & 1023;
        XP[(t*64 + bb)*1024 + n] = f2bf(acc[mt][nt][r] + bias);
      }
    }
  }
}

// ---------------------------------------------------------------- recurrence
// 128 WGs = 8 batch-groups (8 rows) x 16 col-groups (64 cols); runtime XCD
// purity verification (correctness never assumes placement).
// LOCAL protocol (pure group, all on one XCD) — R6 lesson: flag store and
// flag poll MUST meet at the same physical cache level.
//   producer: plain h stores (write-through L1 -> dirty line in shared XCD
//             L2) -> vmcnt(0) -> barrier -> tid0 publishes the flag TWICE:
//             (a) plain workgroup-scope store  -> lands in the SAME XCD L2,
//             (b) agent-scope sc1 store        -> lands at the LLC (R4 path).
//   consumer: lanes 0-15 of every wave poll (a) with sc0 inline-asm loads
//             (L1 bypassed, served by the shared XCD L2, ~300cy); every
//             16th iteration also read (b) via agent-scope load (LLC,
//             R4-proven) and take the max. Progress is guaranteed by (b)
//             even if the L2 model is wrong; (a) makes detection fast.
// MIXED group -> R3-proven agent-scope fallback (sc1 h stores + RELEASE
// fetch_add + counter spin).
__global__ __launch_bounds__(256) void k_rnn(
    const float* __restrict__ Whh, const unsigned short* __restrict__ XP,
    unsigned short* __restrict__ HS, unsigned* __restrict__ ctrl){
  __shared__ unsigned short hlds[8][1032];
  const int wg = blockIdx.x;
  const int gi = wg & 7;            // batch-group (XCD under round-robin)
  const int gj = wg >> 3;           // rank within group / col-group
  const int bi = gi*8, cj = gj*64;
  const int tid = threadIdx.x, w = tid>>6, l = tid&63;
  const int kbase = (l>>4)*8;
  unsigned* flags  = ctrl + 1024;               // L2 flags:  (gi*16+rank)*32 (128B apart)
  unsigned* flagsL = ctrl + 12288;              // LLC flags: same layout
  unsigned* fc     = ctrl + 8192 + gi*32;       // fallback counter

  // --- registration: publish XCD id, barrier, verify group purity ---
  unsigned xcd;
  asm volatile("s_getreg_b32 %0, hwreg(HW_REG_XCC_ID)" : "=s"(xcd));
  xcd = (xcd & 0xffu) | 0x100u;                 // tag so 0 != "unwritten"
  if (tid==0){
    __hip_atomic_store(&ctrl[16+wg], xcd, __ATOMIC_RELAXED, __HIP_MEMORY_SCOPE_AGENT);
    __hip_atomic_fetch_add(&ctrl[0], 1u, __ATOMIC_RELEASE, __HIP_MEMORY_SCOPE_AGENT);
    while (__hip_atomic_load(&ctrl[0], __ATOMIC_RELAXED, __HIP_MEMORY_SCOPE_AGENT) < 128u){}
  }
  __syncthreads();
  bool ok = true;
  if (l < 16){
    unsigned peer = __hip_atomic_load(&ctrl[16 + l*8 + gi], __ATOMIC_RELAXED, __HIP_MEMORY_SCOPE_AGENT);
    ok = (peer == xcd);
  }
  const bool local = __all(ok);

  // --- W_hh slice as resident MFMA B-fragments (128 VGPR/lane) ---
  const int col = cj + w*16 + (l&15);
  s16x8 wf[32];
  #pragma unroll
  for (int kk=0; kk<32; kk++){
    const float* p = Whh + col*1024 + kk*32 + kbase;
    float4 v0 = *(const float4*)p;
    float4 v1 = *(const float4*)(p+4);
    s16x8 s;
    s[0]=(short)f2bf(v0.x); s[1]=(short)f2bf(v0.y); s[2]=(short)f2bf(v0.z); s[3]=(short)f2bf(v0.w);
    s[4]=(short)f2bf(v1.x); s[5]=(short)f2bf(v1.y); s[6]=(short)f2bf(v1.z); s[7]=(short)f2bf(v1.w);
    wf[kk]=s;
  }

  const int ecol = cj + w*16 + (l&15);
  // --- step 0: h = tanh(xp_0) ---
  if (l < 32){
    #pragma unroll
    for (int r=0;r<4;r++){
      int row = (l>>4)*4 + r;                   // 0..7
      float xv = bf2f(XP[(bi+row)*1024 + ecol]);
      unsigned short hv = f2bf(tanhf(xv));
      if (local) HS[((bi+row)*1024 + 0)*1024 + ecol] = hv;
      else __hip_atomic_store(&HS[((bi+row)*1024+0)*1024+ecol], hv,
                              __ATOMIC_RELAXED, __HIP_MEMORY_SCOPE_AGENT);
    }
  }
  asm volatile("s_waitcnt vmcnt(0)" ::: "memory");
  __syncthreads();
  if (tid==0){
    if (local){
      __hip_atomic_store(&flags[(gi*16+gj)*32], 1u,
                         __ATOMIC_RELAXED, __HIP_MEMORY_SCOPE_WORKGROUP);  // plain -> XCD L2
      __hip_atomic_store(&flagsL[(gi*16+gj)*32], 1u,
                         __ATOMIC_RELAXED, __HIP_MEMORY_SCOPE_AGENT);      // sc1 -> LLC
    } else {
      __hip_atomic_fetch_add(fc, 1u, __ATOMIC_RELEASE, __HIP_MEMORY_SCOPE_AGENT);
    }
  }

  for (int s=1; s<1024; ++s){
    // --- wait for h_{s-1} ---
    if (local){
      const unsigned* fpL2  = &flags [(gi*16 + (l&15))*32];
      const unsigned* fpLLC = &flagsL[(gi*16 + (l&15))*32];
      unsigned it = 0;
      for(;;){
        unsigned v = 0xFFFFFFFFu;
        if (l < 16){
          v = ld_flag_sc0(fpL2);
          if (((++it) & 15u) == 0u){
            unsigned v2 = __hip_atomic_load(fpLLC, __ATOMIC_RELAXED, __HIP_MEMORY_SCOPE_AGENT);
            v = (v > v2) ? v : v2;
          }
        }
        if (__all(v >= (unsigned)s)) break;
      }
    } else {
      if (tid==0){
        while (__hip_atomic_load(fc, __ATOMIC_RELAXED, __HIP_MEMORY_SCOPE_AGENT) < 16u*(unsigned)s){}
      }
      __syncthreads();
    }
    // --- xp prefetch: issued here, consumed in epilogue (hides under stage+MFMA)
    float xv[4];
    if (l < 32){
      #pragma unroll
      for (int r=0;r<4;r++)
        xv[r] = bf2f(XP[(s*64 + bi + (l>>4)*4 + r)*1024 + ecol]);
    }
    // --- stage h_{s-1}: each wave stages its 2 rows (coalesced 16B, L2-local) ---
    {
      int r0 = w*2 + (l>>5);
      int c0 = (l&31)*8;
      const unsigned short* rowp = HS + ((bi + r0)*1024 + (s-1))*1024;
      #pragma unroll
      for (int j=0;j<4;j++)
        *(uint4*)&hlds[r0][c0 + j*256] = *(const uint4*)(rowp + c0 + j*256);
    }
    __syncthreads();
    // --- 32 MFMA, 4 independent chains ---
    const int arow = (l&15)&7;
    fx4 ac0 = {0.f,0.f,0.f,0.f}, ac1 = ac0, ac2 = ac0, ac3 = ac0;
    #pragma unroll
    for (int kk=0;kk<32;kk+=4){
      s16x8 a0 = *(const s16x8*)&hlds[arow][(kk+0)*32 + kbase];
      s16x8 a1 = *(const s16x8*)&hlds[arow][(kk+1)*32 + kbase];
      s16x8 a2 = *(const s16x8*)&hlds[arow][(kk+2)*32 + kbase];
      s16x8 a3 = *(const s16x8*)&hlds[arow][(kk+3)*32 + kbase];
      ac0 = __builtin_amdgcn_mfma_f32_16x16x32_bf16(a0, wf[kk+0], ac0, 0,0,0);
      ac1 = __builtin_amdgcn_mfma_f32_16x16x32_bf16(a1, wf[kk+1], ac1, 0,0,0);
      ac2 = __builtin_amdgcn_mfma_f32_16x16x32_bf16(a2, wf[kk+2], ac2, 0,0,0);
      ac3 = __builtin_amdgcn_mfma_f32_16x16x32_bf16(a3, wf[kk+3], ac3, 0,0,0);
    }
    fx4 acc = (ac0+ac1)+(ac2+ac3);
    // --- epilogue: h_s = tanh(acc + xp) ---
    if (l < 32){
      #pragma unroll
      for (int r=0;r<4;r++){
        int row = (l>>4)*4 + r;
        float h = tanhf(acc[r] + xv[r]);
        unsigned short hv = f2bf(h);
        if (local) HS[((bi+row)*1024 + s)*1024 + ecol] = hv;
        else __hip_atomic_store(&HS[((bi+row)*1024+s)*1024+ecol], hv,
                                __ATOMIC_RELAXED, __HIP_MEMORY_SCOPE_AGENT);
      }
    }
    asm volatile("s_waitcnt vmcnt(0)" ::: "memory");
    __syncthreads();
    if (tid==0){
      if (local){
        __hip_atomic_store(&flags[(gi*16+gj)*32], (unsigned)(s+1),
                           __ATOMIC_RELAXED, __HIP_MEMORY_SCOPE_WORKGROUP);  // XCD L2
        __hip_atomic_store(&flagsL[(gi*16+gj)*32], (unsigned)(s+1),
                           __ATOMIC_RELAXED, __HIP_MEMORY_SCOPE_AGENT);      // LLC
      } else {
        __hip_atomic_fetch_add(fc, 1u, __ATOMIC_RELEASE, __HIP_MEMORY_SCOPE_AGENT);
      }
    }
  }
}

// ---------------------------------------------------------------- GEMM2: out = hs@W_out^T + b_out
__global__ __launch_bounds__(512) void k_gemm_out(
    const unsigned short* __restrict__ HS, const unsigned short* __restrict__ WoutB,
    const float* __restrict__ bout, float* __restrict__ OUT){
  __shared__ unsigned short As[128][40];
  __shared__ unsigned short Bs[512][40];
  const int m0 = blockIdx.x*128;
  const int tid = threadIdx.x, w = tid>>6, l = tid&63;
  const int wm = w>>2, wn = w&3;
  fx4 acc[4][8] = {};
  for (int kb = 0; kb < 1024; kb += 32){
    {
      int row = tid>>2, c8 = (tid&3)*8;
      *(uint4*)&As[row][c8] = *(const uint4*)(HS + (m0+row)*1024 + kb + c8);
    }
    #pragma unroll
    for (int q=0;q<4;q++){
      int f = tid + q*512;
      int row = f>>2, c8 = (f&3)*8;
      *(uint4*)&Bs[row][c8] = *(const uint4*)(WoutB + row*1024 + kb + c8);
    }
    __syncthreads();
    const int kbase = (l>>4)*8;
    s16x8 a[4], b[8];
    #pragma unroll
    for (int mt=0;mt<4;mt++) a[mt] = *(const s16x8*)&As[wm*64 + mt*16 + (l&15)][kbase];
    #pragma unroll
    for (int nt=0;nt<8;nt++) b[nt] = *(const s16x8*)&Bs[wn*128 + nt*16 + (l&15)][kbase];
    #pragma unroll
    for (int mt=0;mt<4;mt++)
      #pragma unroll
      for (int nt=0;nt<8;nt++)
        acc[mt][nt] = __builtin_amdgcn_mfma_f32_16x16x32_bf16(a[mt], b[nt], acc[mt][nt], 0,0,0);
    __syncthreads();
  }
  #pragma unroll
  for (int nt=0;nt<8;nt++){
    int n = wn*128 + nt*16 + (l&15);
    float bias = bout[n];
    #pragma unroll
    for (int mt=0;mt<4;mt++){
      #pragma unroll
      for (int r=0;r<4;r++){
        int row = m0 + wm*64 + mt*16 + (l>>4)*4 + r;
        OUT[row*512 + n] = acc[mt][nt][r] + bias;
      }
    }
  }
}

// ---------------------------------------------------------------- launch
extern "C" void kernel_launch(void* const* d_in, const int* in_sizes, int n_in,
                              void* d_out, int out_size, void* d_ws, size_t ws_size,
                              hipStream_t stream){
  const float* x    = (const float*)d_in[0];
  const float* Wih  = (const float*)d_in[1];
  const float* Whh  = (const float*)d_in[2];
  const float* bih  = (const float*)d_in[3];
  const float* bhh  = (const float*)d_in[4];
  const float* Wout = (const float*)d_in[5];
  const float* bout = (const float*)d_in[6];

  const size_t XP_BYTES = 134217728ull;            // bf16 xp, [T][B][H]
  unsigned short* XP    = (unsigned short*)d_ws;
  unsigned short* WoutB = (unsigned short*)((char*)d_ws + XP_BYTES);
  unsigned*       ctrl  = (unsigned*)((char*)d_ws + XP_BYTES + 1048576ull);
  unsigned short* HS    = (unsigned short*)d_out;  // hs bf16 lives in d_out
  float*          OUT   = (float*)d_out;

  hipMemsetAsync(ctrl, 0, 65536, stream);
  k_cvt_wout<<<512, 256, 0, stream>>>(Wout, WoutB);
  dim3 g1(512, 8);
  k_gemm_xp<<<g1, 256, 0, stream>>>(x, Wih, bih, bhh, XP);
  k_rnn<<<128, 256, 0, stream>>>(Whh, XP, HS, ctrl);
  k_gemm_out<<<512, 512, 0, stream>>>(HS, WoutB, bout, OUT);
}

// Round 8
// 3472.404 us; speedup vs baseline: 1.3962x; 1.3962x over previous
//
#include <hip/hip_runtime.h>

typedef __attribute__((ext_vector_type(8))) short s16x8;
typedef __attribute__((ext_vector_type(4))) float fx4;

static __device__ __forceinline__ unsigned short f2bf(float f){
  unsigned u = __float_as_uint(f);
  return (unsigned short)((u + 0x7fffu + ((u>>16)&1u)) >> 16);   // RNE
}
static __device__ __forceinline__ float bf2f(unsigned short s){
  return __uint_as_float(((unsigned)s)<<16);
}
// two 16B LLC-point loads (sc1), single drain. R6/R7 lesson: cross-WG data
// on gfx950 is only HW-coherent at the LLC -> always read it with sc1.
static __device__ __forceinline__ void ld2_g128_sc1(const void* p0, const void* p1,
                                                    uint4* o0, uint4* o1){
  uint4 a, b;
  asm volatile("global_load_dwordx4 %0, %2, off sc1\n\t"
               "global_load_dwordx4 %1, %3, off sc1\n\t"
               "s_waitcnt vmcnt(0)"
               : "=&v"(a), "=&v"(b) : "v"(p0), "v"(p1) : "memory");
  *o0 = a; *o1 = b;
}

// ---------------------------------------------------------------- W_out -> bf16
__global__ void k_cvt_wout(const float* __restrict__ w, unsigned short* __restrict__ o){
  int g = blockIdx.x*256 + threadIdx.x;
  int idx = g*4;
  float4 f = *(const float4*)(w + idx);
  unsigned u0 = (unsigned)f2bf(f.x) | ((unsigned)f2bf(f.y)<<16);
  unsigned u1 = (unsigned)f2bf(f.z) | ((unsigned)f2bf(f.w)<<16);
  *(uint2*)(o + idx) = make_uint2(u0, u1);
}

// ---------------------------------------------------------------- GEMM1: xp = x@W_ih^T + (b_ih+b_hh)
__global__ __launch_bounds__(256) void k_gemm_xp(
    const float* __restrict__ X, const float* __restrict__ Wih,
    const float* __restrict__ bih, const float* __restrict__ bhh,
    unsigned short* __restrict__ XP){
  __shared__ unsigned short As[128][40];
  __shared__ unsigned short Bs[128][40];
  const int bm = blockIdx.x, bn = blockIdx.y;
  const int tid = threadIdx.x, w = tid>>6, l = tid&63;
  const int wm = w>>1, wn = w&1;
  const int m0 = bm*128, n0 = bn*128;
  fx4 acc[4][4] = {};
  for (int kb = 0; kb < 512; kb += 32){
    #pragma unroll
    for (int q=0;q<4;q++){
      int f = tid + q*256;
      int row = f>>3, c4 = (f&7)*4;
      float4 v = *(const float4*)(X + (m0+row)*512 + kb + c4);
      unsigned u0 = (unsigned)f2bf(v.x) | ((unsigned)f2bf(v.y)<<16);
      unsigned u1 = (unsigned)f2bf(v.z) | ((unsigned)f2bf(v.w)<<16);
      *(uint2*)&As[row][c4] = make_uint2(u0,u1);
    }
    #pragma unroll
    for (int q=0;q<4;q++){
      int f = tid + q*256;
      int row = f>>3, c4 = (f&7)*4;
      float4 v = *(const float4*)(Wih + (n0+row)*512 + kb + c4);
      unsigned u0 = (unsigned)f2bf(v.x) | ((unsigned)f2bf(v.y)<<16);
      unsigned u1 = (unsigned)f2bf(v.z) | ((unsigned)f2bf(v.w)<<16);
      *(uint2*)&Bs[row][c4] = make_uint2(u0,u1);
    }
    __syncthreads();
    const int kbase = (l>>4)*8;
    s16x8 a[4], b[4];
    #pragma unroll
    for (int mt=0;mt<4;mt++) a[mt] = *(const s16x8*)&As[wm*64 + mt*16 + (l&15)][kbase];
    #pragma unroll
    for (int nt=0;nt<4;nt++) b[nt] = *(const s16x8*)&Bs[wn*64 + nt*16 + (l&15)][kbase];
    #pragma unroll
    for (int mt=0;mt<4;mt++)
      #pragma unroll
      for (int nt=0;nt<4;nt++)
        acc[mt][nt] = __builtin_amdgcn_mfma_f32_16x16x32_bf16(a[mt], b[nt], acc[mt][nt], 0,0,0);
    __syncthreads();
  }
  #pragma unroll
  for (int nt=0;nt<4;nt++){
    int n = n0 + wn*64 + nt*16 + (l&15);
    float bias = bih[n] + bhh[n];
    #pragma unroll
    for (int mt=0;mt<4;mt++){
      #pragma unroll
      for (int r=0;r<4;r++){
        int grow = m0 + wm*64 + mt*16 + (l>>4)*4 + r;   // = b*1024 + t
        int bb = grow >> 10, t = grow & 1023;
        XP[(t*64 + bb)*1024 + n] = f2bf(acc[mt][nt][r] + bias);
      }
    }
  }
}

// ---------------------------------------------------------------- recurrence
// 64 WGs = 8 groups x 8 WGs(512thr, 8 waves). Group gi = {wg : wg%8==gi}
// (one XCD under round-robin; runtime-verified, never assumed).
// Wave owns 16 output cols; W_hh B-frags register-resident (128 VGPR/lane).
// LOCAL protocol — everything cross-WG rides the LLC (sc1), the ONLY
// HW-verified coherent rendezvous (R6: sc1-store/sc0-load deadlocks;
// R7: plain-store/sc0-load invisible):
//   per-wave flags (64/group, 16B apart -> poll coalesces to 8 lines,
//   publishes of one WG hit 1 line). Step: 64-lane sc1 flag poll (__all,
//   no barrier) -> 2x16B sc1 stage loads/thread -> ONE __syncthreads ->
//   32 MFMA -> tanh -> sc1 2B stores -> vmcnt(0) -> per-wave flag publish.
// Race-safety: wave passes poll(s) only after all 64 waves published s,
// which implies they finished reading the prev LDS tile.
// MIXED group -> R3-proven counter fallback.
__global__ __launch_bounds__(512) void k_rnn(
    const float* __restrict__ Whh, const unsigned short* __restrict__ XP,
    unsigned short* __restrict__ HS, unsigned* __restrict__ ctrl){
  __shared__ unsigned short hlds[8][1032];
  const int wg = blockIdx.x;
  const int gi = wg & 7;            // group (XCD under round-robin)
  const int gj = wg >> 3;           // rank in group: col block
  const int bi = gi*8, cj = gj*128;
  const int tid = threadIdx.x, w = tid>>6, l = tid&63;
  const int kbase = (l>>4)*8;
  unsigned* flags = ctrl + 1024;                // group gi: flags + gi*256 (1KB, 8 lines)
  unsigned* fc    = ctrl + 8192 + gi*32;        // fallback counter

  // --- registration: publish XCD id, verify group purity (all waves) ---
  unsigned xcd;
  asm volatile("s_getreg_b32 %0, hwreg(HW_REG_XCC_ID)" : "=s"(xcd));
  xcd = (xcd & 0xffu) | 0x100u;
  if (tid==0){
    __hip_atomic_store(&ctrl[16+wg], xcd, __ATOMIC_RELAXED, __HIP_MEMORY_SCOPE_AGENT);
    __hip_atomic_fetch_add(&ctrl[0], 1u, __ATOMIC_RELEASE, __HIP_MEMORY_SCOPE_AGENT);
    while (__hip_atomic_load(&ctrl[0], __ATOMIC_RELAXED, __HIP_MEMORY_SCOPE_AGENT) < 64u){}
  }
  __syncthreads();
  bool ok = true;
  if (l < 8){
    unsigned peer = __hip_atomic_load(&ctrl[16 + gi + l*8], __ATOMIC_RELAXED, __HIP_MEMORY_SCOPE_AGENT);
    ok = (peer == xcd);
  }
  const bool local = __all(ok);

  // --- W_hh slice as resident MFMA B-fragments (128 VGPR/lane) ---
  const int col = cj + w*16 + (l&15);
  s16x8 wf[32];
  #pragma unroll
  for (int kk=0; kk<32; kk++){
    const float* p = Whh + col*1024 + kk*32 + kbase;
    float4 v0 = *(const float4*)p;
    float4 v1 = *(const float4*)(p+4);
    s16x8 s;
    s[0]=(short)f2bf(v0.x); s[1]=(short)f2bf(v0.y); s[2]=(short)f2bf(v0.z); s[3]=(short)f2bf(v0.w);
    s[4]=(short)f2bf(v1.x); s[5]=(short)f2bf(v1.y); s[6]=(short)f2bf(v1.z); s[7]=(short)f2bf(v1.w);
    wf[kk]=s;
  }

  const int ecol = cj + w*16 + (l&15);
  unsigned* myflag = &flags[gi*256 + gj*32 + w*4];

  // --- step 0: h0 = tanh(xp_0) for this WG's 8 rows x 128 cols ---
  {
    int e = tid*2;
    int row = e>>7, c = e&127;
    unsigned short h0 = f2bf(tanhf(bf2f(XP[(bi+row)*1024 + cj + c])));
    unsigned short h1 = f2bf(tanhf(bf2f(XP[(bi+row)*1024 + cj + c + 1])));
    unsigned pk = (unsigned)h0 | ((unsigned)h1<<16);
    __hip_atomic_store((unsigned*)&HS[((bi+row)*1024 + 0)*1024 + cj + c], pk,
                       __ATOMIC_RELAXED, __HIP_MEMORY_SCOPE_AGENT);
  }
  asm volatile("s_waitcnt vmcnt(0)" ::: "memory");
  if (local){
    if (l==0) __hip_atomic_store(myflag, 1u, __ATOMIC_RELAXED, __HIP_MEMORY_SCOPE_AGENT);
  } else {
    __syncthreads();
    if (tid==0) __hip_atomic_fetch_add(fc, 1u, __ATOMIC_RELEASE, __HIP_MEMORY_SCOPE_AGENT);
  }

  for (int s=1; s<1024; ++s){
    // xp prefetch (consumed in epilogue; drains into first poll iter, L2-warm)
    float xv[4];
    if (l < 32){
      #pragma unroll
      for (int r=0;r<4;r++)
        xv[r] = bf2f(XP[(s*64 + bi + (l>>4)*4 + r)*1024 + ecol]);
    }
    // --- wait for h_{s-1}: per-wave 64-lane sc1 flag poll (no barrier) ---
    if (local){
      const unsigned* fp = &flags[gi*256 + l*4];   // lane l watches WG l>>3, wave l&7
      for(;;){
        unsigned v = __hip_atomic_load(fp, __ATOMIC_RELAXED, __HIP_MEMORY_SCOPE_AGENT);
        if (__all(v >= (unsigned)s)) break;
      }
    } else {
      if (tid==0){
        while (__hip_atomic_load(fc, __ATOMIC_RELAXED, __HIP_MEMORY_SCOPE_AGENT) < 8u*(unsigned)s){}
      }
      __syncthreads();
    }
    // --- stage h_{s-1}: 8 rows x 2KB, 2x16B sc1 loads per thread ---
    {
      int row = tid>>6, c8 = (tid&63)*16;
      const unsigned short* rowp = HS + ((bi+row)*1024 + (s-1))*1024 + c8;
      uint4 v0, v1;
      ld2_g128_sc1(rowp, rowp+8, &v0, &v1);
      *(uint4*)&hlds[row][c8]     = v0;
      *(uint4*)&hlds[row][c8 + 8] = v1;
    }
    __syncthreads();
    // --- 32 MFMA, 4 independent chains ---
    const int arow = (l&15)&7;
    fx4 ac0 = {0.f,0.f,0.f,0.f}, ac1 = ac0, ac2 = ac0, ac3 = ac0;
    #pragma unroll
    for (int kk=0;kk<32;kk+=4){
      s16x8 a0 = *(const s16x8*)&hlds[arow][(kk+0)*32 + kbase];
      s16x8 a1 = *(const s16x8*)&hlds[arow][(kk+1)*32 + kbase];
      s16x8 a2 = *(const s16x8*)&hlds[arow][(kk+2)*32 + kbase];
      s16x8 a3 = *(const s16x8*)&hlds[arow][(kk+3)*32 + kbase];
      ac0 = __builtin_amdgcn_mfma_f32_16x16x32_bf16(a0, wf[kk+0], ac0, 0,0,0);
      ac1 = __builtin_amdgcn_mfma_f32_16x16x32_bf16(a1, wf[kk+1], ac1, 0,0,0);
      ac2 = __builtin_amdgcn_mfma_f32_16x16x32_bf16(a2, wf[kk+2], ac2, 0,0,0);
      ac3 = __builtin_amdgcn_mfma_f32_16x16x32_bf16(a3, wf[kk+3], ac3, 0,0,0);
    }
    fx4 acc = (ac0+ac1)+(ac2+ac3);
    // --- epilogue: h_s = tanh(acc + xp), sc1 2B stores (rows 0-7 -> l<32) ---
    if (l < 32){
      #pragma unroll
      for (int r=0;r<4;r++){
        int row = (l>>4)*4 + r;
        unsigned short hv = f2bf(tanhf(acc[r] + xv[r]));
        __hip_atomic_store(&HS[((bi+row)*1024 + s)*1024 + ecol], hv,
                           __ATOMIC_RELAXED, __HIP_MEMORY_SCOPE_AGENT);
      }
    }
    asm volatile("s_waitcnt vmcnt(0)" ::: "memory");
    // --- publish ---
    if (local){
      if (l==0) __hip_atomic_store(myflag, (unsigned)(s+1),
                                   __ATOMIC_RELAXED, __HIP_MEMORY_SCOPE_AGENT);
    } else {
      __syncthreads();
      if (tid==0) __hip_atomic_fetch_add(fc, 1u, __ATOMIC_RELEASE, __HIP_MEMORY_SCOPE_AGENT);
    }
  }
}

// ---------------------------------------------------------------- GEMM2: out = hs@W_out^T + b_out
__global__ __launch_bounds__(512) void k_gemm_out(
    const unsigned short* __restrict__ HS, const unsigned short* __restrict__ WoutB,
    const float* __restrict__ bout, float* __restrict__ OUT){
  __shared__ unsigned short As[128][40];
  __shared__ unsigned short Bs[512][40];
  const int m0 = blockIdx.x*128;
  const int tid = threadIdx.x, w = tid>>6, l = tid&63;
  const int wm = w>>2, wn = w&3;
  fx4 acc[4][8] = {};
  for (int kb = 0; kb < 1024; kb += 32){
    {
      int row = tid>>2, c8 = (tid&3)*8;
      *(uint4*)&As[row][c8] = *(const uint4*)(HS + (m0+row)*1024 + kb + c8);
    }
    #pragma unroll
    for (int q=0;q<4;q++){
      int f = tid + q*512;
      int row = f>>2, c8 = (f&3)*8;
      *(uint4*)&Bs[row][c8] = *(const uint4*)(WoutB + row*1024 + kb + c8);
    }
    __syncthreads();
    const int kbase = (l>>4)*8;
    s16x8 a[4], b[8];
    #pragma unroll
    for (int mt=0;mt<4;mt++) a[mt] = *(const s16x8*)&As[wm*64 + mt*16 + (l&15)][kbase];
    #pragma unroll
    for (int nt=0;nt<8;nt++) b[nt] = *(const s16x8*)&Bs[wn*128 + nt*16 + (l&15)][kbase];
    #pragma unroll
    for (int mt=0;mt<4;mt++)
      #pragma unroll
      for (int nt=0;nt<8;nt++)
        acc[mt][nt] = __builtin_amdgcn_mfma_f32_16x16x32_bf16(a[mt], b[nt], acc[mt][nt], 0,0,0);
    __syncthreads();
  }
  #pragma unroll
  for (int nt=0;nt<8;nt++){
    int n = wn*128 + nt*16 + (l&15);
    float bias = bout[n];
    #pragma unroll
    for (int mt=0;mt<4;mt++){
      #pragma unroll
      for (int r=0;r<4;r++){
        int row = m0 + wm*64 + mt*16 + (l>>4)*4 + r;
        OUT[row*512 + n] = acc[mt][nt][r] + bias;
      }
    }
  }
}

// ---------------------------------------------------------------- launch
extern "C" void kernel_launch(void* const* d_in, const int* in_sizes, int n_in,
                              void* d_out, int out_size, void* d_ws, size_t ws_size,
                              hipStream_t stream){
  const float* x    = (const float*)d_in[0];
  const float* Wih  = (const float*)d_in[1];
  const float* Whh  = (const float*)d_in[2];
  const float* bih  = (const float*)d_in[3];
  const float* bhh  = (const float*)d_in[4];
  const float* Wout = (const float*)d_in[5];
  const float* bout = (const float*)d_in[6];

  const size_t XP_BYTES = 134217728ull;            // bf16 xp, [T][B][H]
  unsigned short* XP    = (unsigned short*)d_ws;
  unsigned short* WoutB = (unsigned short*)((char*)d_ws + XP_BYTES);
  unsigned*       ctrl  = (unsigned*)((char*)d_ws + XP_BYTES + 1048576ull);
  unsigned short* HS    = (unsigned short*)d_out;  // hs bf16 lives in d_out
  float*          OUT   = (float*)d_out;

  hipMemsetAsync(ctrl, 0, 65536, stream);
  k_cvt_wout<<<512, 256, 0, stream>>>(Wout, WoutB);
  dim3 g1(512, 8);
  k_gemm_xp<<<g1, 256, 0, stream>>>(x, Wih, bih, bhh, XP);
  k_rnn<<<64, 512, 0, stream>>>(Whh, XP, HS, ctrl);
  k_gemm_out<<<512, 512, 0, stream>>>(HS, WoutB, bout, OUT);
}

// Round 9
// 2919.686 us; speedup vs baseline: 1.6605x; 1.1893x over previous
//
#include <hip/hip_runtime.h>

typedef __attribute__((ext_vector_type(8))) short s16x8;
typedef __attribute__((ext_vector_type(4))) float fx4;

static __device__ __forceinline__ unsigned short f2bf(float f){
  unsigned u = __float_as_uint(f);
  return (unsigned short)((u + 0x7fffu + ((u>>16)&1u)) >> 16);   // RNE
}
static __device__ __forceinline__ float bf2f(unsigned short s){
  return __uint_as_float(((unsigned)s)<<16);
}
// Two 16B LLC-point loads (sc0+sc1 = agent scope: bypass L1 AND L2, read the
// LLC). asm volatile + memory clobber => re-executed every poll iteration.
// R4-R8 lessons: (1) cross-XCD data is only HW-coherent at the LLC; (2) a
// polled address must be re-read at the LLC every iteration (sc0-only or
// plain loads can be served stale); (3) flag+data as separate objects costs
// two serialized LLC round trips -> embed validity IN the data (poison).
static __device__ __forceinline__ void ld2_llc(const void* p0, const void* p1,
                                               uint4* o0, uint4* o1){
  uint4 a, b;
  asm volatile("global_load_dwordx4 %0, %2, off sc0 sc1\n\t"
               "global_load_dwordx4 %1, %3, off sc0 sc1\n\t"
               "s_waitcnt vmcnt(0)"
               : "=&v"(a), "=&v"(b) : "v"(p0), "v"(p1) : "memory");
  *o0 = a; *o1 = b;
}

// ---------------------------------------------------------------- W_out -> bf16
__global__ void k_cvt_wout(const float* __restrict__ w, unsigned short* __restrict__ o){
  int g = blockIdx.x*256 + threadIdx.x;
  int idx = g*4;
  float4 f = *(const float4*)(w + idx);
  unsigned u0 = (unsigned)f2bf(f.x) | ((unsigned)f2bf(f.y)<<16);
  unsigned u1 = (unsigned)f2bf(f.z) | ((unsigned)f2bf(f.w)<<16);
  *(uint2*)(o + idx) = make_uint2(u0, u1);
}

// ---------------------------------------------------------------- GEMM1: xp = x@W_ih^T + (b_ih+b_hh)
__global__ __launch_bounds__(256) void k_gemm_xp(
    const float* __restrict__ X, const float* __restrict__ Wih,
    const float* __restrict__ bih, const float* __restrict__ bhh,
    unsigned short* __restrict__ XP){
  __shared__ unsigned short As[128][40];
  __shared__ unsigned short Bs[128][40];
  const int bm = blockIdx.x, bn = blockIdx.y;
  const int tid = threadIdx.x, w = tid>>6, l = tid&63;
  const int wm = w>>1, wn = w&1;
  const int m0 = bm*128, n0 = bn*128;
  fx4 acc[4][4] = {};
  for (int kb = 0; kb < 512; kb += 32){
    #pragma unroll
    for (int q=0;q<4;q++){
      int f = tid + q*256;
      int row = f>>3, c4 = (f&7)*4;
      float4 v = *(const float4*)(X + (m0+row)*512 + kb + c4);
      unsigned u0 = (unsigned)f2bf(v.x) | ((unsigned)f2bf(v.y)<<16);
      unsigned u1 = (unsigned)f2bf(v.z) | ((unsigned)f2bf(v.w)<<16);
      *(uint2*)&As[row][c4] = make_uint2(u0,u1);
    }
    #pragma unroll
    for (int q=0;q<4;q++){
      int f = tid + q*256;
      int row = f>>3, c4 = (f&7)*4;
      float4 v = *(const float4*)(Wih + (n0+row)*512 + kb + c4);
      unsigned u0 = (unsigned)f2bf(v.x) | ((unsigned)f2bf(v.y)<<16);
      unsigned u1 = (unsigned)f2bf(v.z) | ((unsigned)f2bf(v.w)<<16);
      *(uint2*)&Bs[row][c4] = make_uint2(u0,u1);
    }
    __syncthreads();
    const int kbase = (l>>4)*8;
    s16x8 a[4], b[4];
    #pragma unroll
    for (int mt=0;mt<4;mt++) a[mt] = *(const s16x8*)&As[wm*64 + mt*16 + (l&15)][kbase];
    #pragma unroll
    for (int nt=0;nt<4;nt++) b[nt] = *(const s16x8*)&Bs[wn*64 + nt*16 + (l&15)][kbase];
    #pragma unroll
    for (int mt=0;mt<4;mt++)
      #pragma unroll
      for (int nt=0;nt<4;nt++)
        acc[mt][nt] = __builtin_amdgcn_mfma_f32_16x16x32_bf16(a[mt], b[nt], acc[mt][nt], 0,0,0);
    __syncthreads();
  }
  #pragma unroll
  for (int nt=0;nt<4;nt++){
    int n = n0 + wn*64 + nt*16 + (l&15);
    float bias = bih[n] + bhh[n];
    #pragma unroll
    for (int mt=0;mt<4;mt++){
      #pragma unroll
      for (int r=0;r<4;r++){
        int grow = m0 + wm*64 + mt*16 + (l>>4)*4 + r;   // = b*1024 + t
        int bb = grow >> 10, t = grow & 1023;
        XP[(t*64 + bb)*1024 + n] = f2bf(acc[mt][nt][r] + bias);
      }
    }
  }
}

// ---------------------------------------------------------------- recurrence
// 64 WGs = 8 groups x 8 WGs(512thr, 8 waves). WG owns 8 batch rows x 128
// cols; W_hh B-frags register-resident (128 VGPR/lane).
// POISON-POLL protocol (placement-independent, LLC-coherent, flag-free):
//   HS is pre-poisoned to 0xFFFF (bf16 NaN) by hipMemsetAsync each launch.
//   h = tanh(...) is never NaN, and each HS[row][s][col] address is written
//   exactly once -> "contains a non-poison short" == "final h value".
//   producer: tanh -> sc1 (agent-scope) stores. No drain, no flag.
//   consumer: per-thread polls its own 32B of h_{s-1} with sc0+sc1 16B
//   loads until poison-free, writes LDS, ONE barrier, MFMA.
//   One LLC round trip carries both arrival-detection AND the data.
__global__ __launch_bounds__(512) void k_rnn(
    const float* __restrict__ Whh, const unsigned short* __restrict__ XP,
    unsigned short* __restrict__ HS){
  __shared__ unsigned short hlds[8][1032];
  const int wg = blockIdx.x;
  const int gi = wg & 7;            // batch-group
  const int gj = wg >> 3;           // col block
  const int bi = gi*8, cj = gj*128;
  const int tid = threadIdx.x, w = tid>>6, l = tid&63;
  const int kbase = (l>>4)*8;

  // --- W_hh slice as resident MFMA B-fragments (128 VGPR/lane) ---
  const int col = cj + w*16 + (l&15);
  s16x8 wf[32];
  #pragma unroll
  for (int kk=0; kk<32; kk++){
    const float* p = Whh + col*1024 + kk*32 + kbase;
    float4 v0 = *(const float4*)p;
    float4 v1 = *(const float4*)(p+4);
    s16x8 s;
    s[0]=(short)f2bf(v0.x); s[1]=(short)f2bf(v0.y); s[2]=(short)f2bf(v0.z); s[3]=(short)f2bf(v0.w);
    s[4]=(short)f2bf(v1.x); s[5]=(short)f2bf(v1.y); s[6]=(short)f2bf(v1.z); s[7]=(short)f2bf(v1.w);
    wf[kk]=s;
  }

  const int ecol = cj + w*16 + (l&15);

  // --- step 0: h0 = tanh(xp_0) for this WG's 8 rows x 128 cols ---
  {
    int e = tid*2;
    int row = e>>7, c = e&127;
    unsigned short h0 = f2bf(tanhf(bf2f(XP[(bi+row)*1024 + cj + c])));
    unsigned short h1 = f2bf(tanhf(bf2f(XP[(bi+row)*1024 + cj + c + 1])));
    unsigned pk = (unsigned)h0 | ((unsigned)h1<<16);
    __hip_atomic_store((unsigned*)&HS[((bi+row)*1024 + 0)*1024 + cj + c], pk,
                       __ATOMIC_RELAXED, __HIP_MEMORY_SCOPE_AGENT);
  }

  for (int s=1; s<1024; ++s){
    // xp prefetch (consumed in epilogue; hides under poll+MFMA)
    float xv[4];
    if (l < 32){
      #pragma unroll
      for (int r=0;r<4;r++)
        xv[r] = bf2f(XP[(s*64 + bi + (l>>4)*4 + r)*1024 + ecol]);
    }
    // --- poison-poll + stage h_{s-1}: each thread owns 32B (row, 16 cols) ---
    {
      int row = tid>>6, c8 = (tid&63)*16;
      const unsigned short* rowp = HS + ((bi+row)*1024 + (s-1))*1024 + c8;
      uint4 v0, v1;
      for(;;){
        ld2_llc(rowp, rowp+8, &v0, &v1);
        unsigned bad = 0u;
        #pragma unroll
        for (int j=0;j<4;j++){
          unsigned u = ((unsigned*)&v0)[j];
          bad |= (unsigned)((u & 0xFFFFu) == 0xFFFFu) | (unsigned)(u >= 0xFFFF0000u);
        }
        #pragma unroll
        for (int j=0;j<4;j++){
          unsigned u = ((unsigned*)&v1)[j];
          bad |= (unsigned)((u & 0xFFFFu) == 0xFFFFu) | (unsigned)(u >= 0xFFFF0000u);
        }
        if (!bad) break;
      }
      *(uint4*)&hlds[row][c8]     = v0;
      *(uint4*)&hlds[row][c8 + 8] = v1;
    }
    __syncthreads();
    // --- 32 MFMA, 4 independent chains ---
    const int arow = (l&15)&7;
    fx4 ac0 = {0.f,0.f,0.f,0.f}, ac1 = ac0, ac2 = ac0, ac3 = ac0;
    #pragma unroll
    for (int kk=0;kk<32;kk+=4){
      s16x8 a0 = *(const s16x8*)&hlds[arow][(kk+0)*32 + kbase];
      s16x8 a1 = *(const s16x8*)&hlds[arow][(kk+1)*32 + kbase];
      s16x8 a2 = *(const s16x8*)&hlds[arow][(kk+2)*32 + kbase];
      s16x8 a3 = *(const s16x8*)&hlds[arow][(kk+3)*32 + kbase];
      ac0 = __builtin_amdgcn_mfma_f32_16x16x32_bf16(a0, wf[kk+0], ac0, 0,0,0);
      ac1 = __builtin_amdgcn_mfma_f32_16x16x32_bf16(a1, wf[kk+1], ac1, 0,0,0);
      ac2 = __builtin_amdgcn_mfma_f32_16x16x32_bf16(a2, wf[kk+2], ac2, 0,0,0);
      ac3 = __builtin_amdgcn_mfma_f32_16x16x32_bf16(a3, wf[kk+3], ac3, 0,0,0);
    }
    fx4 acc = (ac0+ac1)+(ac2+ac3);
    // --- epilogue: h_s = tanh(acc + xp), sc1 stores (self-announcing) ---
    if (l < 32){
      #pragma unroll
      for (int r=0;r<4;r++){
        int row = (l>>4)*4 + r;
        unsigned short hv = f2bf(tanhf(acc[r] + xv[r]));
        __hip_atomic_store(&HS[((bi+row)*1024 + s)*1024 + ecol], hv,
                           __ATOMIC_RELAXED, __HIP_MEMORY_SCOPE_AGENT);
      }
    }
    // no drain, no flag, no trailing barrier: the poll in step s+1 (and the
    // __syncthreads above) provide all needed ordering.
  }
}

// ---------------------------------------------------------------- GEMM2: out = hs@W_out^T + b_out
__global__ __launch_bounds__(512) void k_gemm_out(
    const unsigned short* __restrict__ HS, const unsigned short* __restrict__ WoutB,
    const float* __restrict__ bout, float* __restrict__ OUT){
  __shared__ unsigned short As[128][40];
  __shared__ unsigned short Bs[512][40];
  const int m0 = blockIdx.x*128;
  const int tid = threadIdx.x, w = tid>>6, l = tid&63;
  const int wm = w>>2, wn = w&3;
  fx4 acc[4][8] = {};
  for (int kb = 0; kb < 1024; kb += 32){
    {
      int row = tid>>2, c8 = (tid&3)*8;
      *(uint4*)&As[row][c8] = *(const uint4*)(HS + (m0+row)*1024 + kb + c8);
    }
    #pragma unroll
    for (int q=0;q<4;q++){
      int f = tid + q*512;
      int row = f>>2, c8 = (f&3)*8;
      *(uint4*)&Bs[row][c8] = *(const uint4*)(WoutB + row*1024 + kb + c8);
    }
    __syncthreads();
    const int kbase = (l>>4)*8;
    s16x8 a[4], b[8];
    #pragma unroll
    for (int mt=0;mt<4;mt++) a[mt] = *(const s16x8*)&As[wm*64 + mt*16 + (l&15)][kbase];
    #pragma unroll
    for (int nt=0;nt<8;nt++) b[nt] = *(const s16x8*)&Bs[wn*128 + nt*16 + (l&15)][kbase];
    #pragma unroll
    for (int mt=0;mt<4;mt++)
      #pragma unroll
      for (int nt=0;nt<8;nt++)
        acc[mt][nt] = __builtin_amdgcn_mfma_f32_16x16x32_bf16(a[mt], b[nt], acc[mt][nt], 0,0,0);
    __syncthreads();
  }
  #pragma unroll
  for (int nt=0;nt<8;nt++){
    int n = wn*128 + nt*16 + (l&15);
    float bias = bout[n];
    #pragma unroll
    for (int mt=0;mt<4;mt++){
      #pragma unroll
      for (int r=0;r<4;r++){
        int row = m0 + wm*64 + mt*16 + (l>>4)*4 + r;
        OUT[row*512 + n] = acc[mt][nt][r] + bias;
      }
    }
  }
}

// ---------------------------------------------------------------- launch
extern "C" void kernel_launch(void* const* d_in, const int* in_sizes, int n_in,
                              void* d_out, int out_size, void* d_ws, size_t ws_size,
                              hipStream_t stream){
  const float* x    = (const float*)d_in[0];
  const float* Wih  = (const float*)d_in[1];
  const float* Whh  = (const float*)d_in[2];
  const float* bih  = (const float*)d_in[3];
  const float* bhh  = (const float*)d_in[4];
  const float* Wout = (const float*)d_in[5];
  const float* bout = (const float*)d_in[6];

  const size_t XP_BYTES = 134217728ull;            // bf16 xp, [T][B][H]
  unsigned short* XP    = (unsigned short*)d_ws;
  unsigned short* WoutB = (unsigned short*)((char*)d_ws + XP_BYTES);
  unsigned short* HS    = (unsigned short*)d_out;  // hs bf16 lives in d_out
  float*          OUT   = (float*)d_out;

  k_cvt_wout<<<512, 256, 0, stream>>>(Wout, WoutB);
  dim3 g1(512, 8);
  k_gemm_xp<<<g1, 256, 0, stream>>>(x, Wih, bih, bhh, XP);
  // poison HS: 0xFF bytes -> every bf16 short is NaN (0xFFFF); tanh output
  // can never be NaN, so non-poison == final value (self-announcing data).
  hipMemsetAsync(HS, 0xFF, 134217728ull, stream);
  k_rnn<<<64, 512, 0, stream>>>(Whh, XP, HS);
  k_gemm_out<<<512, 512, 0, stream>>>(HS, WoutB, bout, OUT);
}